// Round 12
// baseline (485.674 us; speedup 1.0000x reference)
//
#include <hip/hip_runtime.h>
#include <math.h>

// BEVEncoderLayer: bf16-MFMA pipeline (round 12 — audited round-4 source, resubmitted).
//   qkv: {qp,kp} = (bevq+bev_pos) @ Wq/Wk^T + b ; vp = bevq @ Wv^T + b   (1 launch, grid.z=3)
//   attn_out = MHA(qp,kp,vp)                              (bf16 MFMA flash)
//   y = attn_out @ Wo^T + bo ; x = LN(bevq + y)
//   value = img @ val_w^T ; off/awl = (x+bev_pos) @ {off_w,attn_w}^T     (add fused in staging)
//   samp = msdeform(value, off, awl, ref)                 (fp32 gather)
//   ca = samp @ ca_out_w^T ; x2 = LN(x + ca)
//   h1 = relu(x2 @ W1^T) ; h2 = h1 @ W2^T ; out = LN(x2 + h2)

#define LQ_N 4096
#define LV_N 5376

typedef short short8 __attribute__((ext_vector_type(8)));
typedef float f32x4 __attribute__((ext_vector_type(4)));

__device__ inline unsigned short f2b(float f) {
  union { float f; unsigned u; } v;
  v.f = f;
  return (unsigned short)((v.u + 0x7FFFu + ((v.u >> 16) & 1u)) >> 16);
}

// ------------- bf16 MFMA GEMM body: C[M,N] = (A(+A2))[M,K] @ W[N,K]^T + bias -
// 64x64 tile, 4 waves (wave w owns rows w*16..w*16+15), BK=32.
// LDS rows padded to 40 bf16 (80 B) -> 2-way bank aliasing only (free).
__device__ __forceinline__ void gemm_body(
    const float* __restrict__ A, const float* __restrict__ A2,
    const float* __restrict__ W, const float* __restrict__ bias,
    float* __restrict__ C, int M, int N, int K, int relu, int bm, int bn) {
  __shared__ unsigned short Asb[64][40];
  __shared__ unsigned short Wsb[64][40];
  const int tid = threadIdx.x;
  const int w = tid >> 6, lane = tid & 63;
  const int g = lane >> 4, li = lane & 15;
  f32x4 acc[4] = {{0.f, 0.f, 0.f, 0.f}, {0.f, 0.f, 0.f, 0.f},
                  {0.f, 0.f, 0.f, 0.f}, {0.f, 0.f, 0.f, 0.f}};
  for (int k0 = 0; k0 < K; k0 += 32) {
    __syncthreads();
#pragma unroll
    for (int i = 0; i < 2; ++i) {
      int r = (tid >> 3) + i * 32;
      int c = (tid & 7) * 4;
      int gr = bm + r;
      float4 av = make_float4(0.f, 0.f, 0.f, 0.f);
      if (gr < M) {
        av = *reinterpret_cast<const float4*>(&A[(size_t)gr * K + k0 + c]);
        if (A2) {
          float4 bv = *reinterpret_cast<const float4*>(&A2[(size_t)gr * K + k0 + c]);
          av.x += bv.x; av.y += bv.y; av.z += bv.z; av.w += bv.w;
        }
      }
      Asb[r][c + 0] = f2b(av.x); Asb[r][c + 1] = f2b(av.y);
      Asb[r][c + 2] = f2b(av.z); Asb[r][c + 3] = f2b(av.w);
      int gw = bn + r;
      float4 wv = make_float4(0.f, 0.f, 0.f, 0.f);
      if (gw < N) wv = *reinterpret_cast<const float4*>(&W[(size_t)gw * K + k0 + c]);
      Wsb[r][c + 0] = f2b(wv.x); Wsb[r][c + 1] = f2b(wv.y);
      Wsb[r][c + 2] = f2b(wv.z); Wsb[r][c + 3] = f2b(wv.w);
    }
    __syncthreads();
    short8 af = *reinterpret_cast<const short8*>(&Asb[w * 16 + li][g * 8]);
#pragma unroll
    for (int nt = 0; nt < 4; ++nt) {
      short8 wf = *reinterpret_cast<const short8*>(&Wsb[nt * 16 + li][g * 8]);
      acc[nt] = __builtin_amdgcn_mfma_f32_16x16x32_bf16(af, wf, acc[nt], 0, 0, 0);
    }
  }
#pragma unroll
  for (int nt = 0; nt < 4; ++nt) {
#pragma unroll
    for (int reg = 0; reg < 4; ++reg) {
      int row = bm + w * 16 + g * 4 + reg;
      int col = bn + nt * 16 + li;
      if (row < M && col < N) {
        float v = acc[nt][reg] + bias[col];
        if (relu) v = fmaxf(v, 0.f);
        C[(size_t)row * N + col] = v;
      }
    }
  }
}

__global__ __launch_bounds__(256) void gemm_bf16_kernel(
    const float* __restrict__ A, const float* __restrict__ A2,
    const float* __restrict__ W, const float* __restrict__ bias,
    float* __restrict__ C, int M, int N, int K, int relu) {
  gemm_body(A, A2, W, bias, C, M, N, K, relu, blockIdx.y * 64, blockIdx.x * 64);
}

// QKV: z=0 -> qp=(bevq+pos)Wq^T, z=1 -> kp=(bevq+pos)Wk^T, z=2 -> vp=bevq Wv^T
__global__ __launch_bounds__(256) void qkv_kernel(
    const float* __restrict__ bevq, const float* __restrict__ bevpos,
    const float* __restrict__ w, const float* __restrict__ b,
    float* __restrict__ out) {
  const int z = blockIdx.z;
  gemm_body(bevq, z < 2 ? bevpos : nullptr, w + (size_t)z * 256 * 256, b + z * 256,
            out + (size_t)z * 1048576, LQ_N, 256, 256, 0,
            blockIdx.y * 64, blockIdx.x * 64);
}

// ---------------- bf16 MFMA flash attention ----------------
// grid (LQ/64, H); block 256 = 4 waves; wave w owns q-rows w*16..w*16+15.
// Softmax scale folded into Q at staging.
__global__ __launch_bounds__(256) void attn_mfma_kernel(
    const float* __restrict__ qp, const float* __restrict__ kp,
    const float* __restrict__ vp, float* __restrict__ out) {
  const int h = blockIdx.y;
  const int q0 = blockIdx.x * 64;
  __shared__ unsigned short Qsb[64][40];
  __shared__ unsigned short Ksb[64][40];
  __shared__ unsigned short Vtb[32][72];   // transposed V: [dh][key]
  __shared__ unsigned short Plds[4][16][72];
  const int tid = threadIdx.x;
  const int w = tid >> 6, lane = tid & 63;
  const int g = lane >> 4, li = lane & 15;
  const float scale = 0.17677669529663687f;  // 1/sqrt(32)

  // stage Q (scaled)
#pragma unroll
  for (int i = 0; i < 2; ++i) {
    int r = (tid >> 3) + i * 32;
    int c = (tid & 7) * 4;
    float4 v = *reinterpret_cast<const float4*>(&qp[(size_t)(q0 + r) * 256 + h * 32 + c]);
    Qsb[r][c + 0] = f2b(v.x * scale); Qsb[r][c + 1] = f2b(v.y * scale);
    Qsb[r][c + 2] = f2b(v.z * scale); Qsb[r][c + 3] = f2b(v.w * scale);
  }
  __syncthreads();
  short8 qfrag = *reinterpret_cast<const short8*>(&Qsb[w * 16 + li][g * 8]);

  f32x4 oacc[2] = {{0.f, 0.f, 0.f, 0.f}, {0.f, 0.f, 0.f, 0.f}};
  float m_run[4] = {-1e30f, -1e30f, -1e30f, -1e30f};
  float l_run[4] = {0.f, 0.f, 0.f, 0.f};

  for (int kt = 0; kt < LQ_N; kt += 64) {
    __syncthreads();  // previous tile's Ksb/Vtb readers done
    // stage K and V^T (bf16)
#pragma unroll
    for (int i = 0; i < 2; ++i) {
      int r = (tid >> 3) + i * 32;
      int c = (tid & 7) * 4;
      float4 kv = *reinterpret_cast<const float4*>(&kp[(size_t)(kt + r) * 256 + h * 32 + c]);
      Ksb[r][c + 0] = f2b(kv.x); Ksb[r][c + 1] = f2b(kv.y);
      Ksb[r][c + 2] = f2b(kv.z); Ksb[r][c + 3] = f2b(kv.w);
      float4 vv = *reinterpret_cast<const float4*>(&vp[(size_t)(kt + r) * 256 + h * 32 + c]);
      Vtb[c + 0][r] = f2b(vv.x); Vtb[c + 1][r] = f2b(vv.y);
      Vtb[c + 2][r] = f2b(vv.z); Vtb[c + 3][r] = f2b(vv.w);
    }
    __syncthreads();

    // S = (Q*scale) K^T : 4 MFMAs per wave (16 q-rows x 64 keys)
    f32x4 s[4];
#pragma unroll
    for (int nt = 0; nt < 4; ++nt) {
      short8 kf = *reinterpret_cast<const short8*>(&Ksb[nt * 16 + li][g * 8]);
      f32x4 z = {0.f, 0.f, 0.f, 0.f};
      s[nt] = __builtin_amdgcn_mfma_f32_16x16x32_bf16(qfrag, kf, z, 0, 0, 0);
    }

    // online softmax: lane holds rows g*4+reg (cols nt*16+li)
#pragma unroll
    for (int reg = 0; reg < 4; ++reg) {
      float m = fmaxf(fmaxf(s[0][reg], s[1][reg]), fmaxf(s[2][reg], s[3][reg]));
      m = fmaxf(m, __shfl_xor(m, 1));
      m = fmaxf(m, __shfl_xor(m, 2));
      m = fmaxf(m, __shfl_xor(m, 4));
      m = fmaxf(m, __shfl_xor(m, 8));
      float mn = fmaxf(m_run[reg], m);
      float corr = __expf(m_run[reg] - mn);
      m_run[reg] = mn;
      float ls = 0.f;
#pragma unroll
      for (int nt = 0; nt < 4; ++nt) {
        float p = __expf(s[nt][reg] - mn);
        s[nt][reg] = p;
        ls += p;
      }
      ls += __shfl_xor(ls, 1);
      ls += __shfl_xor(ls, 2);
      ls += __shfl_xor(ls, 4);
      ls += __shfl_xor(ls, 8);
      l_run[reg] = l_run[reg] * corr + ls;
#pragma unroll
      for (int nt = 0; nt < 4; ++nt)
        Plds[w][g * 4 + reg][nt * 16 + li] = f2b(s[nt][reg]);
      oacc[0][reg] *= corr;
      oacc[1][reg] *= corr;
    }

    // PV: O[16 x 32] += P[16 x 64] @ V[64 x 32]
    // (same-wave LDS write->read: DS pipe is in-order per wave)
#pragma unroll
    for (int ks = 0; ks < 2; ++ks) {
      short8 pf = *reinterpret_cast<const short8*>(&Plds[w][li][ks * 32 + g * 8]);
#pragma unroll
      for (int nt2 = 0; nt2 < 2; ++nt2) {
        short8 vf = *reinterpret_cast<const short8*>(&Vtb[nt2 * 16 + li][ks * 32 + g * 8]);
        oacc[nt2] = __builtin_amdgcn_mfma_f32_16x16x32_bf16(pf, vf, oacc[nt2], 0, 0, 0);
      }
    }
  }

#pragma unroll
  for (int reg = 0; reg < 4; ++reg) {
    float invl = 1.f / l_run[reg];
    int row = q0 + w * 16 + g * 4 + reg;
#pragma unroll
    for (int nt2 = 0; nt2 < 2; ++nt2)
      out[(size_t)row * 256 + h * 32 + nt2 * 16 + li] = oacc[nt2][reg] * invl;
  }
}

// ---------------- add + LayerNorm (row = 256) ----------------
__global__ __launch_bounds__(256) void add_ln_kernel(
    const float* __restrict__ a, const float* __restrict__ b,
    const float* __restrict__ g, const float* __restrict__ bb,
    float* __restrict__ out) {
  int row = blockIdx.x, t = threadIdx.x;
  float v = a[(size_t)row * 256 + t] + b[(size_t)row * 256 + t];
  float s = v;
#pragma unroll
  for (int m = 32; m >= 1; m >>= 1) s += __shfl_xor(s, m);
  __shared__ float red[4], red2[4];
  int wave = t >> 6, lane = t & 63;
  if (lane == 0) red[wave] = s;
  __syncthreads();
  float mean = (red[0] + red[1] + red[2] + red[3]) * (1.f / 256.f);
  float dv = v - mean;
  float s2 = dv * dv;
#pragma unroll
  for (int m = 32; m >= 1; m >>= 1) s2 += __shfl_xor(s2, m);
  if (lane == 0) red2[wave] = s2;
  __syncthreads();
  float var = (red2[0] + red2[1] + red2[2] + red2[3]) * (1.f / 256.f);
  out[(size_t)row * 256 + t] = dv * rsqrtf(var + 1e-5f) * g[t] + bb[t];
}

// ---------------- msdeform sampling ----------------
// grid LQ, block 256: thread = (h = tid>>5, d = tid&31).
__global__ __launch_bounds__(256) void msdeform_kernel(
    const float* __restrict__ value,  // [LV, 256] feature = h*32+d
    const float* __restrict__ off,    // [LQ, 192]
    const float* __restrict__ awl,    // [LQ, 96]
    const float* __restrict__ ref,    // [LQ, 3, 2]
    float* __restrict__ out) {        // [LQ, 256]
  int qi = blockIdx.x;
  int tid = threadIdx.x;
  int h = tid >> 5, d = tid & 31;
  float w[12];
  float mx = -1e30f;
#pragma unroll
  for (int j = 0; j < 12; ++j) {
    w[j] = awl[(size_t)qi * 96 + h * 12 + j];
    mx = fmaxf(mx, w[j]);
  }
  float ssum = 0.f;
#pragma unroll
  for (int j = 0; j < 12; ++j) {
    w[j] = __expf(w[j] - mx);
    ssum += w[j];
  }
  float inv = 1.f / ssum;
  const int starts[3] = {0, 4096, 5120};
  const int dims[3] = {64, 32, 16};
  float acc = 0.f;
#pragma unroll
  for (int l = 0; l < 3; ++l) {
    const int Wl = dims[l], Hl = dims[l];
    float rx = ref[(size_t)qi * 6 + l * 2 + 0];
    float ry = ref[(size_t)qi * 6 + l * 2 + 1];
    auto fetch = [&](int xi, int yi) -> float {
      if (xi < 0 || xi >= Wl || yi < 0 || yi >= Hl) return 0.f;
      return value[(size_t)(starts[l] + yi * Wl + xi) * 256 + h * 32 + d];
    };
#pragma unroll
    for (int p = 0; p < 4; ++p) {
      int oidx = qi * 192 + ((h * 3 + l) * 4 + p) * 2;
      float ox = off[oidx], oy = off[oidx + 1];
      float x = (rx + ox / (float)Wl) * (float)Wl - 0.5f;
      float y = (ry + oy / (float)Hl) * (float)Hl - 0.5f;
      float x0f = floorf(x), y0f = floorf(y);
      float wx = x - x0f, wy = y - y0f;
      int x0 = (int)x0f, y0 = (int)y0f;
      float g00 = fetch(x0, y0);
      float g01 = fetch(x0 + 1, y0);
      float g10 = fetch(x0, y0 + 1);
      float g11 = fetch(x0 + 1, y0 + 1);
      float samp = g00 * (1.f - wx) * (1.f - wy) + g01 * wx * (1.f - wy) +
                   g10 * (1.f - wx) * wy + g11 * wx * wy;
      acc += samp * w[l * 4 + p] * inv;
    }
  }
  out[(size_t)qi * 256 + h * 32 + d] = acc;
}

extern "C" void kernel_launch(void* const* d_in, const int* in_sizes, int n_in,
                              void* d_out, int out_size, void* d_ws, size_t ws_size,
                              hipStream_t stream) {
  const float* bevq   = (const float*)d_in[0];
  const float* img    = (const float*)d_in[1];
  const float* refp   = (const float*)d_in[2];
  // d_in[3] = spatial_shapes (unused, static)
  const float* bevpos = (const float*)d_in[4];
  const float* mha_in_w  = (const float*)d_in[5];
  const float* mha_in_b  = (const float*)d_in[6];
  const float* mha_out_w = (const float*)d_in[7];
  const float* mha_out_b = (const float*)d_in[8];
  const float* norm1_g = (const float*)d_in[9];
  const float* norm1_b = (const float*)d_in[10];
  const float* off_w  = (const float*)d_in[11];
  const float* off_b  = (const float*)d_in[12];
  const float* attn_w = (const float*)d_in[13];
  const float* attn_b = (const float*)d_in[14];
  const float* val_w  = (const float*)d_in[15];
  const float* val_b  = (const float*)d_in[16];
  const float* ca_out_w = (const float*)d_in[17];
  const float* ca_out_b = (const float*)d_in[18];
  const float* norm2_g = (const float*)d_in[19];
  const float* norm2_b = (const float*)d_in[20];
  const float* ffn_w1 = (const float*)d_in[21];
  const float* ffn_b1 = (const float*)d_in[22];
  const float* ffn_w2 = (const float*)d_in[23];
  const float* ffn_b2 = (const float*)d_in[24];
  const float* ffn_g  = (const float*)d_in[25];
  const float* ffn_bb = (const float*)d_in[26];

  float* ws = (float*)d_ws;
  const size_t M1 = 1048576;  // 4096*256
  float* bufQP  = ws + 1 * M1;     // qp -> off
  float* bufKP  = ws + 2 * M1;     // kp -> awl
  float* bufVP  = ws + 3 * M1;     // vp
  float* bufAO  = ws + 4 * M1;     // attn_out -> samp
  float* bufX   = ws + 5 * M1;     // x
  float* bufX2  = ws + 6 * M1;     // x2
  float* bufH1  = ws + 7 * M1;     // h1 (2M)
  float* bufVAL = ws + 9 * M1;     // value (5376*256)
  float* bufY   = ws;              // generic GEMM output scratch

  float* out = (float*)d_out;

  dim3 blk(256);
  // qp/kp/vp projections (q-add fused for z<2)
  qkv_kernel<<<dim3(4, 64, 3), blk, 0, stream>>>(bevq, bevpos, mha_in_w, mha_in_b, bufQP);
  // attention
  attn_mfma_kernel<<<dim3(64, 8), blk, 0, stream>>>(bufQP, bufKP, bufVP, bufAO);
  // out-proj ; x = LN(bevq + y)
  gemm_bf16_kernel<<<dim3(4, 64), blk, 0, stream>>>(bufAO, nullptr, mha_out_w, mha_out_b,
                                                    bufY, LQ_N, 256, 256, 0);
  add_ln_kernel<<<dim3(4096), blk, 0, stream>>>(bevq, bufY, norm1_g, norm1_b, bufX);
  // value / off / awl projections ((x+bev_pos) fused into A-staging)
  gemm_bf16_kernel<<<dim3(4, 84), blk, 0, stream>>>(img, nullptr, val_w, val_b,
                                                    bufVAL, LV_N, 256, 256, 0);
  gemm_bf16_kernel<<<dim3(3, 64), blk, 0, stream>>>(bufX, bevpos, off_w, off_b,
                                                    bufQP, LQ_N, 192, 256, 0);
  gemm_bf16_kernel<<<dim3(2, 64), blk, 0, stream>>>(bufX, bevpos, attn_w, attn_b,
                                                    bufKP, LQ_N, 96, 256, 0);
  // msdeform sampling
  msdeform_kernel<<<dim3(4096), blk, 0, stream>>>(bufVAL, bufQP, bufKP, refp, bufAO);
  // ca out-proj ; x2 = LN(x + ca)
  gemm_bf16_kernel<<<dim3(4, 64), blk, 0, stream>>>(bufAO, nullptr, ca_out_w, ca_out_b,
                                                    bufY, LQ_N, 256, 256, 0);
  add_ln_kernel<<<dim3(4096), blk, 0, stream>>>(bufX, bufY, norm2_g, norm2_b, bufX2);
  // FFN
  gemm_bf16_kernel<<<dim3(8, 64), blk, 0, stream>>>(bufX2, nullptr, ffn_w1, ffn_b1,
                                                    bufH1, LQ_N, 512, 256, 1);
  gemm_bf16_kernel<<<dim3(4, 64), blk, 0, stream>>>(bufH1, nullptr, ffn_w2, ffn_b2,
                                                    bufY, LQ_N, 256, 512, 0);
  add_ln_kernel<<<dim3(4096), blk, 0, stream>>>(bufX2, bufY, ffn_g, ffn_bb, out);

  (void)in_sizes; (void)n_in; (void)out_size; (void)ws_size;
}

// Round 15
// 428.684 us; speedup vs baseline: 1.1329x; 1.1329x over previous
//
#include <hip/hip_runtime.h>
#include <math.h>

// BEVEncoderLayer round 15: barrier-free bf16 attention (round-13 source, re-audited twice).
//   qkv GEMM -> bf16 {q(scaled),k,v} ; transpose v -> vT[256][4096]
//   attn: K/V fragments direct from global (L2), P via per-wave LDS, NO syncthreads
//   rest of pipeline unchanged (fp32 GEMMs, LN, msdeform).

#define LQ_N 4096
#define LV_N 5376

typedef short short8 __attribute__((ext_vector_type(8)));
typedef float f32x4 __attribute__((ext_vector_type(4)));

__device__ inline unsigned short f2b(float f) {
  union { float f; unsigned u; } v;
  v.f = f;
  return (unsigned short)((v.u + 0x7FFFu + ((v.u >> 16) & 1u)) >> 16);
}

// ------------- bf16 MFMA GEMM body: C[M,N] = (A(+A2))[M,K] @ W[N,K]^T + bias -
// mode: 0 = f32 out, 1 = f32+relu, 2 = bf16 out scaled by oscale.
__device__ __forceinline__ void gemm_body(
    const float* __restrict__ A, const float* __restrict__ A2,
    const float* __restrict__ W, const float* __restrict__ bias,
    void* __restrict__ C, int M, int N, int K, int mode, float oscale,
    int bm, int bn) {
  __shared__ unsigned short Asb[64][40];
  __shared__ unsigned short Wsb[64][40];
  const int tid = threadIdx.x;
  const int w = tid >> 6, lane = tid & 63;
  const int g = lane >> 4, li = lane & 15;
  f32x4 acc[4] = {{0.f, 0.f, 0.f, 0.f}, {0.f, 0.f, 0.f, 0.f},
                  {0.f, 0.f, 0.f, 0.f}, {0.f, 0.f, 0.f, 0.f}};
  for (int k0 = 0; k0 < K; k0 += 32) {
    __syncthreads();
#pragma unroll
    for (int i = 0; i < 2; ++i) {
      int r = (tid >> 3) + i * 32;
      int c = (tid & 7) * 4;
      int gr = bm + r;
      float4 av = make_float4(0.f, 0.f, 0.f, 0.f);
      if (gr < M) {
        av = *reinterpret_cast<const float4*>(&A[(size_t)gr * K + k0 + c]);
        if (A2) {
          float4 bv = *reinterpret_cast<const float4*>(&A2[(size_t)gr * K + k0 + c]);
          av.x += bv.x; av.y += bv.y; av.z += bv.z; av.w += bv.w;
        }
      }
      Asb[r][c + 0] = f2b(av.x); Asb[r][c + 1] = f2b(av.y);
      Asb[r][c + 2] = f2b(av.z); Asb[r][c + 3] = f2b(av.w);
      int gw = bn + r;
      float4 wv = make_float4(0.f, 0.f, 0.f, 0.f);
      if (gw < N) wv = *reinterpret_cast<const float4*>(&W[(size_t)gw * K + k0 + c]);
      Wsb[r][c + 0] = f2b(wv.x); Wsb[r][c + 1] = f2b(wv.y);
      Wsb[r][c + 2] = f2b(wv.z); Wsb[r][c + 3] = f2b(wv.w);
    }
    __syncthreads();
    short8 af = *reinterpret_cast<const short8*>(&Asb[w * 16 + li][g * 8]);
#pragma unroll
    for (int nt = 0; nt < 4; ++nt) {
      short8 wf = *reinterpret_cast<const short8*>(&Wsb[nt * 16 + li][g * 8]);
      acc[nt] = __builtin_amdgcn_mfma_f32_16x16x32_bf16(af, wf, acc[nt], 0, 0, 0);
    }
  }
#pragma unroll
  for (int nt = 0; nt < 4; ++nt) {
#pragma unroll
    for (int reg = 0; reg < 4; ++reg) {
      int row = bm + w * 16 + g * 4 + reg;
      int col = bn + nt * 16 + li;
      if (row < M && col < N) {
        float v = acc[nt][reg] + bias[col];
        if (mode == 1) v = fmaxf(v, 0.f);
        if (mode == 2)
          ((unsigned short*)C)[(size_t)row * N + col] = f2b(v * oscale);
        else
          ((float*)C)[(size_t)row * N + col] = v;
      }
    }
  }
}

__global__ __launch_bounds__(256) void gemm_bf16_kernel(
    const float* __restrict__ A, const float* __restrict__ A2,
    const float* __restrict__ W, const float* __restrict__ bias,
    float* __restrict__ C, int M, int N, int K, int relu) {
  gemm_body(A, A2, W, bias, C, M, N, K, relu, 1.f,
            blockIdx.y * 64, blockIdx.x * 64);
}

// QKV -> bf16: z=0 qp=(bevq+pos)Wq^T scaled by 1/sqrt(32); z=1 kp; z=2 vp.
__global__ __launch_bounds__(256) void qkv_kernel(
    const float* __restrict__ bevq, const float* __restrict__ bevpos,
    const float* __restrict__ w, const float* __restrict__ b,
    unsigned short* __restrict__ out) {
  const int z = blockIdx.z;
  float sc = (z == 0) ? 0.17677669529663687f : 1.0f;
  gemm_body(bevq, z < 2 ? bevpos : nullptr, w + (size_t)z * 256 * 256, b + z * 256,
            out + (size_t)z * 1048576, LQ_N, 256, 256, 2, sc,
            blockIdx.y * 64, blockIdx.x * 64);
}

// ---------------- bf16 transpose: in[4096][256] -> out[256][4096] ----------
// 64x64 tiles, XOR-swizzled LDS (write scatter conflict-free, read b128 aligned).
__global__ __launch_bounds__(256) void transpose_bf16_kernel(
    const unsigned short* __restrict__ in, unsigned short* __restrict__ out) {
  __shared__ unsigned short t[64][72];
  const int tid = threadIdx.x;
  const int bx = blockIdx.x;  // token tile (64 of them)
  const int by = blockIdx.y;  // feature tile (4 of them)
#pragma unroll
  for (int i = 0; i < 2; ++i) {
    int r = (tid >> 3) + i * 32;   // token-local
    int c = (tid & 7) * 8;         // feature-local
    short8 v = *reinterpret_cast<const short8*>(
        &in[(size_t)(bx * 64 + r) * 256 + by * 64 + c]);
#pragma unroll
    for (int j = 0; j < 8; ++j) {
      int A = c + j;
      int f = (A ^ (A >> 3)) & 7;
      t[A][r ^ (f << 3)] = (unsigned short)v[j];
    }
  }
  __syncthreads();
#pragma unroll
  for (int i = 0; i < 2; ++i) {
    int r2 = (tid >> 3) + i * 32;  // feature-local
    int c2 = (tid & 7) * 8;        // token-local
    int f = (r2 ^ (r2 >> 3)) & 7;
    short8 v = *reinterpret_cast<const short8*>(&t[r2][c2 ^ (f << 3)]);
    *reinterpret_cast<short8*>(
        &out[(size_t)(by * 64 + r2) * 4096 + bx * 64 + c2]) = v;
  }
}

// ---------------- barrier-free bf16 MFMA flash attention ----------------
// grid (LQ/64, H); block 256 = 4 waves; wave w owns q-rows w*16..w*16+15.
// K,V fragments loaded directly from global (L2-resident); P via per-wave LDS
// (same-wave DS ordering, validated in round 12). Zero __syncthreads.
__global__ __launch_bounds__(256) void attn_mfma_kernel(
    const unsigned short* __restrict__ qb, const unsigned short* __restrict__ kb,
    const unsigned short* __restrict__ vt, float* __restrict__ out) {
  const int h = blockIdx.y;
  const int q0 = blockIdx.x * 64;
  __shared__ unsigned short Plds[4][16][136];
  const int tid = threadIdx.x;
  const int w = tid >> 6, lane = tid & 63;
  const int g = lane >> 4, li = lane & 15;

  // Q fragment direct from global (Q is pre-scaled bf16)
  short8 qfrag = *reinterpret_cast<const short8*>(
      &qb[(size_t)(q0 + w * 16 + li) * 256 + h * 32 + g * 8]);

  f32x4 oacc[2] = {{0.f, 0.f, 0.f, 0.f}, {0.f, 0.f, 0.f, 0.f}};
  float m_run[4] = {-1e30f, -1e30f, -1e30f, -1e30f};
  float l_run[4] = {0.f, 0.f, 0.f, 0.f};

  const unsigned short* kbase = kb + h * 32 + g * 8;
  const unsigned short* vbase = vt + (size_t)(h * 32) * 4096;
  const int pswz = (li & 7) << 3;

  for (int kt = 0; kt < LQ_N; kt += 128) {
    // S = Q K^T over 128 keys: 8 MFMAs, K fragments direct from global
    f32x4 s[8];
    __builtin_amdgcn_s_setprio(1);
#pragma unroll
    for (int nt = 0; nt < 8; ++nt) {
      short8 kf = *reinterpret_cast<const short8*>(
          &kbase[(size_t)(kt + nt * 16 + li) * 256]);
      f32x4 z = {0.f, 0.f, 0.f, 0.f};
      s[nt] = __builtin_amdgcn_mfma_f32_16x16x32_bf16(qfrag, kf, z, 0, 0, 0);
    }
    __builtin_amdgcn_s_setprio(0);

    // online softmax (rows g*4+reg distributed over 16 lanes li)
#pragma unroll
    for (int reg = 0; reg < 4; ++reg) {
      float m = s[0][reg];
#pragma unroll
      for (int nt = 1; nt < 8; ++nt) m = fmaxf(m, s[nt][reg]);
      m = fmaxf(m, __shfl_xor(m, 1));
      m = fmaxf(m, __shfl_xor(m, 2));
      m = fmaxf(m, __shfl_xor(m, 4));
      m = fmaxf(m, __shfl_xor(m, 8));
      float mn = fmaxf(m_run[reg], m);
      float corr = __expf(m_run[reg] - mn);
      m_run[reg] = mn;
      float ls = 0.f;
      int qr = g * 4 + reg;
      int swz = (qr & 7) << 3;
#pragma unroll
      for (int nt = 0; nt < 8; ++nt) {
        float p = __expf(s[nt][reg] - mn);
        ls += p;
        Plds[w][qr][(nt * 16 + li) ^ swz] = f2b(p);
      }
      ls += __shfl_xor(ls, 1);
      ls += __shfl_xor(ls, 2);
      ls += __shfl_xor(ls, 4);
      ls += __shfl_xor(ls, 8);
      l_run[reg] = l_run[reg] * corr + ls;
      oacc[0][reg] *= corr;
      oacc[1][reg] *= corr;
    }

    // PV: O[16x32] += P[16x128] @ V[128x32]; V fragments from pre-transposed vT
    __builtin_amdgcn_s_setprio(1);
#pragma unroll
    for (int ks = 0; ks < 4; ++ks) {
      short8 pf = *reinterpret_cast<const short8*>(
          &Plds[w][li][(ks * 32 + g * 8) ^ pswz]);
#pragma unroll
      for (int nt2 = 0; nt2 < 2; ++nt2) {
        short8 vf = *reinterpret_cast<const short8*>(
            &vbase[(size_t)(nt2 * 16 + li) * 4096 + kt + ks * 32 + g * 8]);
        oacc[nt2] = __builtin_amdgcn_mfma_f32_16x16x32_bf16(pf, vf, oacc[nt2], 0, 0, 0);
      }
    }
    __builtin_amdgcn_s_setprio(0);
  }

#pragma unroll
  for (int reg = 0; reg < 4; ++reg) {
    float invl = 1.f / l_run[reg];
    int row = q0 + w * 16 + g * 4 + reg;
#pragma unroll
    for (int nt2 = 0; nt2 < 2; ++nt2)
      out[(size_t)row * 256 + h * 32 + nt2 * 16 + li] = oacc[nt2][reg] * invl;
  }
}

// ---------------- add + LayerNorm (row = 256) ----------------
__global__ __launch_bounds__(256) void add_ln_kernel(
    const float* __restrict__ a, const float* __restrict__ b,
    const float* __restrict__ g, const float* __restrict__ bb,
    float* __restrict__ out) {
  int row = blockIdx.x, t = threadIdx.x;
  float v = a[(size_t)row * 256 + t] + b[(size_t)row * 256 + t];
  float s = v;
#pragma unroll
  for (int m = 32; m >= 1; m >>= 1) s += __shfl_xor(s, m);
  __shared__ float red[4], red2[4];
  int wave = t >> 6, lane = t & 63;
  if (lane == 0) red[wave] = s;
  __syncthreads();
  float mean = (red[0] + red[1] + red[2] + red[3]) * (1.f / 256.f);
  float dv = v - mean;
  float s2 = dv * dv;
#pragma unroll
  for (int m = 32; m >= 1; m >>= 1) s2 += __shfl_xor(s2, m);
  if (lane == 0) red2[wave] = s2;
  __syncthreads();
  float var = (red2[0] + red2[1] + red2[2] + red2[3]) * (1.f / 256.f);
  out[(size_t)row * 256 + t] = dv * rsqrtf(var + 1e-5f) * g[t] + bb[t];
}

// ---------------- msdeform sampling ----------------
__global__ __launch_bounds__(256) void msdeform_kernel(
    const float* __restrict__ value,  // [LV, 256] feature = h*32+d
    const float* __restrict__ off,    // [LQ, 192]
    const float* __restrict__ awl,    // [LQ, 96]
    const float* __restrict__ ref,    // [LQ, 3, 2]
    float* __restrict__ out) {        // [LQ, 256]
  int qi = blockIdx.x;
  int tid = threadIdx.x;
  int h = tid >> 5, d = tid & 31;
  float w[12];
  float mx = -1e30f;
#pragma unroll
  for (int j = 0; j < 12; ++j) {
    w[j] = awl[(size_t)qi * 96 + h * 12 + j];
    mx = fmaxf(mx, w[j]);
  }
  float ssum = 0.f;
#pragma unroll
  for (int j = 0; j < 12; ++j) {
    w[j] = __expf(w[j] - mx);
    ssum += w[j];
  }
  float inv = 1.f / ssum;
  const int starts[3] = {0, 4096, 5120};
  const int dims[3] = {64, 32, 16};
  float acc = 0.f;
#pragma unroll
  for (int l = 0; l < 3; ++l) {
    const int Wl = dims[l], Hl = dims[l];
    float rx = ref[(size_t)qi * 6 + l * 2 + 0];
    float ry = ref[(size_t)qi * 6 + l * 2 + 1];
    auto fetch = [&](int xi, int yi) -> float {
      if (xi < 0 || xi >= Wl || yi < 0 || yi >= Hl) return 0.f;
      return value[(size_t)(starts[l] + yi * Wl + xi) * 256 + h * 32 + d];
    };
#pragma unroll
    for (int p = 0; p < 4; ++p) {
      int oidx = qi * 192 + ((h * 3 + l) * 4 + p) * 2;
      float ox = off[oidx], oy = off[oidx + 1];
      float x = (rx + ox / (float)Wl) * (float)Wl - 0.5f;
      float y = (ry + oy / (float)Hl) * (float)Hl - 0.5f;
      float x0f = floorf(x), y0f = floorf(y);
      float wx = x - x0f, wy = y - y0f;
      int x0 = (int)x0f, y0 = (int)y0f;
      float g00 = fetch(x0, y0);
      float g01 = fetch(x0 + 1, y0);
      float g10 = fetch(x0, y0 + 1);
      float g11 = fetch(x0 + 1, y0 + 1);
      float samp = g00 * (1.f - wx) * (1.f - wy) + g01 * wx * (1.f - wy) +
                   g10 * (1.f - wx) * wy + g11 * wx * wy;
      acc += samp * w[l * 4 + p] * inv;
    }
  }
  out[(size_t)qi * 256 + h * 32 + d] = acc;
}

extern "C" void kernel_launch(void* const* d_in, const int* in_sizes, int n_in,
                              void* d_out, int out_size, void* d_ws, size_t ws_size,
                              hipStream_t stream) {
  const float* bevq   = (const float*)d_in[0];
  const float* img    = (const float*)d_in[1];
  const float* refp   = (const float*)d_in[2];
  // d_in[3] = spatial_shapes (unused, static)
  const float* bevpos = (const float*)d_in[4];
  const float* mha_in_w  = (const float*)d_in[5];
  const float* mha_in_b  = (const float*)d_in[6];
  const float* mha_out_w = (const float*)d_in[7];
  const float* mha_out_b = (const float*)d_in[8];
  const float* norm1_g = (const float*)d_in[9];
  const float* norm1_b = (const float*)d_in[10];
  const float* off_w  = (const float*)d_in[11];
  const float* off_b  = (const float*)d_in[12];
  const float* attn_w = (const float*)d_in[13];
  const float* attn_b = (const float*)d_in[14];
  const float* val_w  = (const float*)d_in[15];
  const float* val_b  = (const float*)d_in[16];
  const float* ca_out_w = (const float*)d_in[17];
  const float* ca_out_b = (const float*)d_in[18];
  const float* norm2_g = (const float*)d_in[19];
  const float* norm2_b = (const float*)d_in[20];
  const float* ffn_w1 = (const float*)d_in[21];
  const float* ffn_b1 = (const float*)d_in[22];
  const float* ffn_w2 = (const float*)d_in[23];
  const float* ffn_b2 = (const float*)d_in[24];
  const float* ffn_g  = (const float*)d_in[25];
  const float* ffn_bb = (const float*)d_in[26];

  float* ws = (float*)d_ws;
  const size_t M1 = 1048576;  // 4096*256
  // layout (stays within round-12's proven footprint of ~10.3*M1 floats):
  float* bufY   = ws;                               // y / awl / ca / h2 scratch
  unsigned short* qkb = (unsigned short*)(ws + 1 * M1);  // q bf16, k bf16 (2x2MB)
  unsigned short* vb  = (unsigned short*)(ws + 2 * M1);  // v bf16, vT bf16 (2x2MB)
  float* bufOFF = ws + 3 * M1;    // off fp32 (3MB)
  float* bufAO  = ws + 4 * M1;    // attn_out -> samp
  float* bufX   = ws + 5 * M1;    // x
  float* bufX2  = ws + 6 * M1;    // x2
  float* bufH1  = ws + 7 * M1;    // h1 (8MB -> [7,9))
  float* bufVAL = ws + 9 * M1;    // value (5376*256)
  float* bufAWL = ws;             // awl reuses bufY low region (y dead by then)

  float* out = (float*)d_out;

  dim3 blk(256);
  // qp/kp/vp projections -> bf16 (q pre-scaled; q-add fused for z<2)
  qkv_kernel<<<dim3(4, 64, 3), blk, 0, stream>>>(bevq, bevpos, mha_in_w, mha_in_b, qkb);
  // v -> vT
  transpose_bf16_kernel<<<dim3(64, 4), blk, 0, stream>>>(vb, vb + 1048576);
  // attention (barrier-free)
  attn_mfma_kernel<<<dim3(64, 8), blk, 0, stream>>>(qkb, qkb + 1048576,
                                                    vb + 1048576, bufAO);
  // out-proj ; x = LN(bevq + y)
  gemm_bf16_kernel<<<dim3(4, 64), blk, 0, stream>>>(bufAO, nullptr, mha_out_w, mha_out_b,
                                                    bufY, LQ_N, 256, 256, 0);
  add_ln_kernel<<<dim3(4096), blk, 0, stream>>>(bevq, bufY, norm1_g, norm1_b, bufX);
  // value / off / awl projections ((x+bev_pos) fused into A-staging)
  gemm_bf16_kernel<<<dim3(4, 84), blk, 0, stream>>>(img, nullptr, val_w, val_b,
                                                    bufVAL, LV_N, 256, 256, 0);
  gemm_bf16_kernel<<<dim3(3, 64), blk, 0, stream>>>(bufX, bevpos, off_w, off_b,
                                                    bufOFF, LQ_N, 192, 256, 0);
  gemm_bf16_kernel<<<dim3(2, 64), blk, 0, stream>>>(bufX, bevpos, attn_w, attn_b,
                                                    bufAWL, LQ_N, 96, 256, 0);
  // msdeform sampling
  msdeform_kernel<<<dim3(4096), blk, 0, stream>>>(bufVAL, bufOFF, bufAWL, refp, bufAO);
  // ca out-proj ; x2 = LN(x + ca)
  gemm_bf16_kernel<<<dim3(4, 64), blk, 0, stream>>>(bufAO, nullptr, ca_out_w, ca_out_b,
                                                    bufY, LQ_N, 256, 256, 0);
  add_ln_kernel<<<dim3(4096), blk, 0, stream>>>(bufX, bufY, norm2_g, norm2_b, bufX2);
  // FFN
  gemm_bf16_kernel<<<dim3(8, 64), blk, 0, stream>>>(bufX2, nullptr, ffn_w1, ffn_b1,
                                                    bufH1, LQ_N, 512, 256, 1);
  gemm_bf16_kernel<<<dim3(4, 64), blk, 0, stream>>>(bufH1, nullptr, ffn_w2, ffn_b2,
                                                    bufY, LQ_N, 256, 512, 0);
  add_ln_kernel<<<dim3(4096), blk, 0, stream>>>(bufX2, bufY, ffn_g, ffn_bb, out);

  (void)in_sizes; (void)n_in; (void)out_size; (void)ws_size;
}